// Round 6
// baseline (350.816 us; speedup 1.0000x reference)
//
#include <hip/hip_runtime.h>
#include <math.h>

#define MUL0 64
#define MUL1 32
#define ROW_F 160          // floats per row of node_input / output
#define EPS2 1.0e-16f      // EPS^2
#define LOG2F_ 0.69314718055994531f
#define LP 65              // LDS transpose pad stride (65 % 32 == 1 -> 2-way max, free)
#define WPB 2              // waves per block
#define TPB (WPB * 64)

// ---------------------------------------------------------------------------
// Kernel 1: combine the three weight matrices per path into one, with the
// normalization constants folded in.
//   ws[0    .. 2048) : W0c (32x64)  = C0 * W_tp_0e @ W_lin_0e @ W_sc_0e
//   ws[2048 .. 4096) : W1c (64x32)  = C1 * W_tp_1o @ W_lin_1o @ W_sc_1o
// ---------------------------------------------------------------------------
#define OT0   0            // Wtp0  32x64  (2048)
#define OL0   2048         // Wlin0 64x64  (4096)
#define OS0   6144         // Wsc0  64x64  (4096)
#define OT1   10240        // Wtp1  64x32  (2048)
#define OL1   12288        // Wlin1 32x32  (1024)
#define OS1   13312        // Wsc1  32x32  (1024)
#define OM0   14336        // tmp0  32x64  (2048)
#define OM1   16384        // tmp1  64x32  (2048)
#define CW_LDS 18432       // floats

__global__ __launch_bounds__(1024)
void combine_weights(const float* __restrict__ Wtp0,   // 32x64
                     const float* __restrict__ Wtp1,   // 64x32
                     const float* __restrict__ Wlin0,  // 64x64
                     const float* __restrict__ Wlin1,  // 32x32
                     const float* __restrict__ Wsc0,   // 64x64
                     const float* __restrict__ Wsc1,   // 32x32
                     float* __restrict__ ws)
{
    __shared__ float L[CW_LDS];
    const int t = threadIdx.x;

    {
        const float* srcs[6] = {Wtp0, Wlin0, Wsc0, Wtp1, Wlin1, Wsc1};
        const int    offs[6] = {OT0, OL0, OS0, OT1, OL1, OS1};
        const int    n4s[6]  = {512, 1024, 1024, 512, 256, 256};
#pragma unroll
        for (int m = 0; m < 6; ++m) {
            const float4* s = (const float4*)srcs[m];
            float4* d = (float4*)(L + offs[m]);
            for (int i = t; i < n4s[m]; i += 1024) d[i] = s[i];
        }
    }
    __syncthreads();

    if (t < 512) {
        const int u = t >> 4, q = t & 15;          // tmp0: 32 rows x 16 quads
        float4 acc = {0.f, 0.f, 0.f, 0.f};
#pragma unroll 8
        for (int k = 0; k < 64; ++k) {
            const float a = L[OT0 + u * 64 + k];
            const float4 b = ((const float4*)(L + OL0))[k * 16 + q];
            acc.x += a * b.x; acc.y += a * b.y; acc.z += a * b.z; acc.w += a * b.w;
        }
        ((float4*)(L + OM0))[u * 16 + q] = acc;
    } else {
        const int t2 = t - 512;
        const int u = t2 >> 3, q = t2 & 7;         // tmp1: 64 rows x 8 quads
        float4 acc = {0.f, 0.f, 0.f, 0.f};
#pragma unroll 8
        for (int k = 0; k < 32; ++k) {
            const float a = L[OT1 + u * 32 + k];
            const float4 b = ((const float4*)(L + OL1))[k * 8 + q];
            acc.x += a * b.x; acc.y += a * b.y; acc.z += a * b.z; acc.w += a * b.w;
        }
        ((float4*)(L + OM1))[u * 8 + q] = acc;
    }
    __syncthreads();

    const float C0 = 1.0f / (sqrtf(96.0f) * 64.0f);
    const float C1 = 1.0f / 256.0f;
    if (t < 512) {
        const int u = t >> 4, q = t & 15;
        float4 acc = {0.f, 0.f, 0.f, 0.f};
#pragma unroll 8
        for (int k = 0; k < 64; ++k) {
            const float a = L[OM0 + u * 64 + k];
            const float4 b = ((const float4*)(L + OS0))[k * 16 + q];
            acc.x += a * b.x; acc.y += a * b.y; acc.z += a * b.z; acc.w += a * b.w;
        }
        acc.x *= C0; acc.y *= C0; acc.z *= C0; acc.w *= C0;
        ((float4*)ws)[u * 16 + q] = acc;
    } else {
        const int t2 = t - 512;
        const int u = t2 >> 3, q = t2 & 7;
        float4 acc = {0.f, 0.f, 0.f, 0.f};
#pragma unroll 8
        for (int k = 0; k < 32; ++k) {
            const float a = L[OM1 + u * 32 + k];
            const float4 b = ((const float4*)(L + OS1))[k * 8 + q];
            acc.x += a * b.x; acc.y += a * b.y; acc.z += a * b.z; acc.w += a * b.w;
        }
        acc.x *= C1; acc.y *= C1; acc.z *= C1; acc.w *= C1;
        ((float4*)(ws + 2048))[u * 8 + q] = acc;
    }
}

// (softplus(n) - log 2) / n   for n > 0
__device__ __forceinline__ float ssp_over_n(float n)
{
    float sp = n + __logf(1.0f + __expf(-n)) - LOG2F_;
    return __fdividef(sp, n);
}

// Wave-local fence: buffer is wave-private; DS pipe is in-order per wave.
__device__ __forceinline__ void wave_fence()
{
    __asm__ volatile("" ::: "memory");
    __builtin_amdgcn_wave_barrier();
}

// ---------------------------------------------------------------------------
// Staging: issue (global->regs, unrolled/static) and commitL (regs->LDS,
// transposed, unrolled/static). Compute reads LDS directly (dynamic LDS
// indexing is free -- never a register array with runtime index).
// buf layout: [col][row], row-stride LP=65.
// ---------------------------------------------------------------------------
template<int W>
struct Stage {
    float4 v[W / 4];

    __device__ __forceinline__ void issue(const float* __restrict__ g,
                                          int lane, int rmax)
    {
        constexpr int NF4 = W / 4;
#pragma unroll
        for (int k = 0; k < NF4; ++k) {
            int id = k * 64 + lane;
            int r = id / NF4, gg = id % NF4;
            int rr = r <= rmax ? r : rmax;     // clamp (dup rows, benign)
            v[k] = *(const float4*)(g + rr * ROW_F + 4 * gg);
        }
    }

    __device__ __forceinline__ void commitL(float* buf, int lane)
    {
        constexpr int NF4 = W / 4;
        wave_fence();                          // WAR vs previous buf consumers
#pragma unroll
        for (int k = 0; k < NF4; ++k) {
            int id = k * 64 + lane;
            int r = id / NF4, gg = id % NF4;
            buf[(4 * gg + 0) * LP + r] = v[k].x;
            buf[(4 * gg + 1) * LP + r] = v[k].y;
            buf[(4 * gg + 2) * LP + r] = v[k].z;
            buf[(4 * gg + 3) * LP + r] = v[k].w;
        }
        wave_fence();
    }
};

// coalesced store of W cols already sitting in buf (transposed read + store)
template<int W>
__device__ __forceinline__ void flushL(float* __restrict__ g, const float* buf,
                                       int lane, int rmax)
{
    constexpr int NF4 = W / 4;
    wave_fence();                          // all lanes' gate writes visible
#pragma unroll
    for (int k = 0; k < NF4; ++k) {
        int id = k * 64 + lane;
        int r = id / NF4, gg = id % NF4;
        int rr = r <= rmax ? r : rmax;     // dup rows write identical data
        float4 o;
        o.x = buf[(4 * gg + 0) * LP + r];
        o.y = buf[(4 * gg + 1) * LP + r];
        o.z = buf[(4 * gg + 2) * LP + r];
        o.w = buf[(4 * gg + 3) * LP + r];
        *(float4*)(g + rr * ROW_F + 4 * gg) = o;
    }
}

// ---------------------------------------------------------------------------
// Kernel 2: 2 waves/block, one row per lane, 25 KB LDS.
// REGISTER BUDGET: peak live ~155 VGPR (z0 phase: acc0+acc1 (64) + XR0/XR1
// in-flight (64) + temps).  __launch_bounds__(TPB, 3) is NOT enough: the
// second arg is only a MINIMUM waves/EU, and the allocator pushed to 6/EU
// (VGPR=84 in r2/r3/r5) spilling ~62 MB/launch to scratch (WRITE_SIZE 190
// vs 132 ideal).  amdgpu_waves_per_eu(3,3) pins the target: VGPR cap 168,
// no occupancy-greedy spilling.  LDS (6 blocks/CU) and VGPR then both give
// 12 waves/CU.
// ---------------------------------------------------------------------------
__global__ __launch_bounds__(TPB) __attribute__((amdgpu_waves_per_eu(3, 3)))
void field_main(const float* __restrict__ in,     // N x 160
                const float* __restrict__ attr,   // N
                const float* __restrict__ field,  // N x 3
                const float* __restrict__ Wg,     // 4096 floats: W0c | W1c
                float* __restrict__ out,          // N x 160
                int nrows)
{
    __shared__ float tbuf[WPB][48 * LP];

    const int tid = threadIdx.x;
    const int wv = tid >> 6, lane = tid & 63;
    int r0 = (blockIdx.x * WPB + wv) * 64;
    if (r0 > nrows - 64) r0 = nrows - 64;          // overflow waves: dup work
    if (r0 < 0) r0 = 0;
    const int rmax = min(63, nrows - 1 - r0);
    const int rowe = r0 + min(lane, rmax);

    const float a  = attr[rowe];
    const float f0 = field[3 * rowe + 0];
    const float f1 = field[3 * rowe + 1];
    const float f2 = field[3 * rowe + 2];
    const float af0 = a * f0, af1 = a * f1, af2 = a * f2;

    const float* gin  = in  + (size_t)r0 * ROW_F;
    float*       gout = out + (size_t)r0 * ROW_F;
    float* buf = tbuf[wv];

    // ---- issue x0 halves + x1 chunk0 together (all in flight) ----
    Stage<32> XA, XB;
    Stage<48> C0;
    XA.issue(gin,      lane, rmax);
    XB.issue(gin + 32, lane, rmax);
    C0.issue(gin + 64, lane, rmax);

    // ---- pw[w] = a * sum_u x0[u] * W1c[u][w]; x0 read from LDS, rolled ----
    float pw[32];
#pragma unroll
    for (int w = 0; w < 32; ++w) pw[w] = 0.f;

    XA.commitL(buf, lane);                 // buf cols 0..31 = x0[0..32)
#pragma unroll 2
    for (int u = 0; u < 32; ++u) {
        const float xu = buf[u * LP + lane];
        const float4* wr = (const float4*)(Wg + 2048 + u * 32);
#pragma unroll
        for (int j = 0; j < 8; ++j) {
            const float4 t = wr[j];
            pw[4 * j + 0] += xu * t.x;
            pw[4 * j + 1] += xu * t.y;
            pw[4 * j + 2] += xu * t.z;
            pw[4 * j + 3] += xu * t.w;
        }
    }
    XB.commitL(buf, lane);                 // buf cols 0..31 = x0[32..64)
#pragma unroll 2
    for (int u = 0; u < 32; ++u) {
        const float xu = buf[u * LP + lane];
        const float4* wr = (const float4*)(Wg + 3072 + u * 32);
#pragma unroll
        for (int j = 0; j < 8; ++j) {
            const float4 t = wr[j];
            pw[4 * j + 0] += xu * t.x;
            pw[4 * j + 1] += xu * t.y;
            pw[4 * j + 2] += xu * t.z;
            pw[4 * j + 3] += xu * t.w;
        }
    }
#pragma unroll
    for (int w = 0; w < 32; ++w) pw[w] *= a;

    // ---- x1 chunks: gate in LDS in-place, s1 in static regs ----
    float s1[32];
    Stage<48> C1;

    // chunk 0 (u = 0..15)
    C0.commitL(buf, lane);
    C1.issue(gin + 64 + 48, lane, rmax);   // chunk1 loads fly under chunk0 work
#pragma unroll
    for (int i = 0; i < 16; ++i) {
        const float m0 = buf[(3 * i + 0) * LP + lane];
        const float m1 = buf[(3 * i + 1) * LP + lane];
        const float m2 = buf[(3 * i + 2) * LP + lane];
        s1[i] = m0 * af0 + m1 * af1 + m2 * af2;
        const float p = pw[i];
        float q0 = m0 + p * f0;
        float q1 = m1 + p * f1;
        float q2 = m2 + p * f2;
        float n = sqrtf(q0 * q0 + q1 * q1 + q2 * q2 + EPS2);
        float t = ssp_over_n(n);
        buf[(3 * i + 0) * LP + lane] = q0 * t;
        buf[(3 * i + 1) * LP + lane] = q1 * t;
        buf[(3 * i + 2) * LP + lane] = q2 * t;
    }
    flushL<48>(gout + 64, buf, lane, rmax);

    // chunk 1 (u = 16..31)
    C1.commitL(buf, lane);
#pragma unroll
    for (int i = 0; i < 16; ++i) {
        const float m0 = buf[(3 * i + 0) * LP + lane];
        const float m1 = buf[(3 * i + 1) * LP + lane];
        const float m2 = buf[(3 * i + 2) * LP + lane];
        s1[16 + i] = m0 * af0 + m1 * af1 + m2 * af2;
        const float p = pw[16 + i];
        float q0 = m0 + p * f0;
        float q1 = m1 + p * f1;
        float q2 = m2 + p * f2;
        float n = sqrtf(q0 * q0 + q1 * q1 + q2 * q2 + EPS2);
        float t = ssp_over_n(n);
        buf[(3 * i + 0) * LP + lane] = q0 * t;
        buf[(3 * i + 1) * LP + lane] = q1 * t;
        buf[(3 * i + 2) * LP + lane] = q2 * t;
    }
    flushL<48>(gout + 64 + 48, buf, lane, rmax);

    // ---- dump s1 to LDS so the z0 matmul can be a rolled loop ----
    wave_fence();
#pragma unroll
    for (int i = 0; i < 32; ++i) buf[i * LP + lane] = s1[i];
    wave_fence();

    // ---- re-issue x0 loads (latency hides under z0 matmul) ----
    Stage<32> XR0, XR1;
    XR0.issue(gin,      lane, rmax);
    XR1.issue(gin + 32, lane, rmax);

    // ---- z0 = s1 @ W0c (both 32-col halves in one rolled loop) ----
    float acc0[32], acc1[32];
#pragma unroll
    for (int j = 0; j < 32; ++j) { acc0[j] = 0.f; acc1[j] = 0.f; }
#pragma unroll 2
    for (int u = 0; u < 32; ++u) {
        const float su = buf[u * LP + lane];
        const float4* wr = (const float4*)(Wg + u * 64);
#pragma unroll
        for (int j = 0; j < 8; ++j) {
            const float4 t = wr[j];
            acc0[4 * j + 0] += su * t.x;
            acc0[4 * j + 1] += su * t.y;
            acc0[4 * j + 2] += su * t.z;
            acc0[4 * j + 3] += su * t.w;
        }
#pragma unroll
        for (int j = 0; j < 8; ++j) {
            const float4 t = wr[8 + j];
            acc1[4 * j + 0] += su * t.x;
            acc1[4 * j + 1] += su * t.y;
            acc1[4 * j + 2] += su * t.z;
            acc1[4 * j + 3] += su * t.w;
        }
    }

    // ---- o0 halves: gate(x0 + z0) with x0 from re-staged LDS ----
    XR0.commitL(buf, lane);                // cols 0..31 = x0[0..32)
#pragma unroll
    for (int j = 0; j < 32; ++j) {
        const float r = buf[j * LP + lane] + acc0[j];
        const float n = sqrtf(r * r + EPS2);
        buf[j * LP + lane] = r * ssp_over_n(n);
    }
    flushL<32>(gout, buf, lane, rmax);

    XR1.commitL(buf, lane);                // cols 0..31 = x0[32..64)
#pragma unroll
    for (int j = 0; j < 32; ++j) {
        const float r = buf[j * LP + lane] + acc1[j];
        const float n = sqrtf(r * r + EPS2);
        buf[j * LP + lane] = r * ssp_over_n(n);
    }
    flushL<32>(gout + 32, buf, lane, rmax);
}

extern "C" void kernel_launch(void* const* d_in, const int* in_sizes, int n_in,
                              void* d_out, int out_size, void* d_ws, size_t ws_size,
                              hipStream_t stream)
{
    const float* node_input = (const float*)d_in[0];
    const float* node_attr  = (const float*)d_in[1];
    const float* field      = (const float*)d_in[2];
    const float* Wtp0       = (const float*)d_in[3];
    const float* Wtp1       = (const float*)d_in[4];
    const float* Wlin0      = (const float*)d_in[5];
    const float* Wlin1      = (const float*)d_in[6];
    const float* Wsc0       = (const float*)d_in[7];
    const float* Wsc1       = (const float*)d_in[8];
    float* out = (float*)d_out;
    float* ws  = (float*)d_ws;

    const int nrows = in_sizes[0] / ROW_F;   // 200000

    hipLaunchKernelGGL(combine_weights, dim3(1), dim3(1024), 0, stream,
                       Wtp0, Wtp1, Wlin0, Wlin1, Wsc0, Wsc1, ws);

    const int nwaves = (nrows + 63) / 64;
    const int nb = (nwaves + WPB - 1) / WPB;
    hipLaunchKernelGGL(field_main, dim3(nb), dim3(TPB), 0, stream,
                       node_input, node_attr, field, ws, out, nrows);
}

// Round 7
// 320.826 us; speedup vs baseline: 1.0935x; 1.0935x over previous
//
#include <hip/hip_runtime.h>
#include <math.h>

#define MUL0 64
#define MUL1 32
#define ROW_F 160          // floats per row of node_input / output
#define EPS2 1.0e-16f      // EPS^2
#define LOG2F_ 0.69314718055994531f
#define LP 65              // LDS transpose pad stride (65 % 32 == 1 -> 2-way max, free)
#define WPB 2              // waves per block
#define TPB (WPB * 64)

// ---------------------------------------------------------------------------
// Kernel 1: combine the three weight matrices per path into one, with the
// normalization constants folded in.
//   ws[0    .. 2048) : W0c (32x64)  = C0 * W_tp_0e @ W_lin_0e @ W_sc_0e
//   ws[2048 .. 4096) : W1c (64x32)  = C1 * W_tp_1o @ W_lin_1o @ W_sc_1o
// ---------------------------------------------------------------------------
#define OT0   0            // Wtp0  32x64  (2048)
#define OL0   2048         // Wlin0 64x64  (4096)
#define OS0   6144         // Wsc0  64x64  (4096)
#define OT1   10240        // Wtp1  64x32  (2048)
#define OL1   12288        // Wlin1 32x32  (1024)
#define OS1   13312        // Wsc1  32x32  (1024)
#define OM0   14336        // tmp0  32x64  (2048)
#define OM1   16384        // tmp1  64x32  (2048)
#define CW_LDS 18432       // floats

__global__ __launch_bounds__(1024)
void combine_weights(const float* __restrict__ Wtp0,   // 32x64
                     const float* __restrict__ Wtp1,   // 64x32
                     const float* __restrict__ Wlin0,  // 64x64
                     const float* __restrict__ Wlin1,  // 32x32
                     const float* __restrict__ Wsc0,   // 64x64
                     const float* __restrict__ Wsc1,   // 32x32
                     float* __restrict__ ws)
{
    __shared__ float L[CW_LDS];
    const int t = threadIdx.x;

    {
        const float* srcs[6] = {Wtp0, Wlin0, Wsc0, Wtp1, Wlin1, Wsc1};
        const int    offs[6] = {OT0, OL0, OS0, OT1, OL1, OS1};
        const int    n4s[6]  = {512, 1024, 1024, 512, 256, 256};
#pragma unroll
        for (int m = 0; m < 6; ++m) {
            const float4* s = (const float4*)srcs[m];
            float4* d = (float4*)(L + offs[m]);
            for (int i = t; i < n4s[m]; i += 1024) d[i] = s[i];
        }
    }
    __syncthreads();

    if (t < 512) {
        const int u = t >> 4, q = t & 15;          // tmp0: 32 rows x 16 quads
        float4 acc = {0.f, 0.f, 0.f, 0.f};
#pragma unroll 8
        for (int k = 0; k < 64; ++k) {
            const float a = L[OT0 + u * 64 + k];
            const float4 b = ((const float4*)(L + OL0))[k * 16 + q];
            acc.x += a * b.x; acc.y += a * b.y; acc.z += a * b.z; acc.w += a * b.w;
        }
        ((float4*)(L + OM0))[u * 16 + q] = acc;
    } else {
        const int t2 = t - 512;
        const int u = t2 >> 3, q = t2 & 7;         // tmp1: 64 rows x 8 quads
        float4 acc = {0.f, 0.f, 0.f, 0.f};
#pragma unroll 8
        for (int k = 0; k < 32; ++k) {
            const float a = L[OT1 + u * 32 + k];
            const float4 b = ((const float4*)(L + OL1))[k * 8 + q];
            acc.x += a * b.x; acc.y += a * b.y; acc.z += a * b.z; acc.w += a * b.w;
        }
        ((float4*)(L + OM1))[u * 8 + q] = acc;
    }
    __syncthreads();

    const float C0 = 1.0f / (sqrtf(96.0f) * 64.0f);
    const float C1 = 1.0f / 256.0f;
    if (t < 512) {
        const int u = t >> 4, q = t & 15;
        float4 acc = {0.f, 0.f, 0.f, 0.f};
#pragma unroll 8
        for (int k = 0; k < 64; ++k) {
            const float a = L[OM0 + u * 64 + k];
            const float4 b = ((const float4*)(L + OS0))[k * 16 + q];
            acc.x += a * b.x; acc.y += a * b.y; acc.z += a * b.z; acc.w += a * b.w;
        }
        acc.x *= C0; acc.y *= C0; acc.z *= C0; acc.w *= C0;
        ((float4*)ws)[u * 16 + q] = acc;
    } else {
        const int t2 = t - 512;
        const int u = t2 >> 3, q = t2 & 7;
        float4 acc = {0.f, 0.f, 0.f, 0.f};
#pragma unroll 8
        for (int k = 0; k < 32; ++k) {
            const float a = L[OM1 + u * 32 + k];
            const float4 b = ((const float4*)(L + OS1))[k * 8 + q];
            acc.x += a * b.x; acc.y += a * b.y; acc.z += a * b.z; acc.w += a * b.w;
        }
        acc.x *= C1; acc.y *= C1; acc.z *= C1; acc.w *= C1;
        ((float4*)(ws + 2048))[u * 8 + q] = acc;
    }
}

// (softplus(n) - log 2) / n   for n > 0
__device__ __forceinline__ float ssp_over_n(float n)
{
    float sp = n + __logf(1.0f + __expf(-n)) - LOG2F_;
    return __fdividef(sp, n);
}

// Wave-local fence: buffer is wave-private; DS pipe is in-order per wave.
__device__ __forceinline__ void wave_fence()
{
    __asm__ volatile("" ::: "memory");
    __builtin_amdgcn_wave_barrier();
}

// ---------------------------------------------------------------------------
// Staging: issue (global->regs, unrolled/static) and commitL (regs->LDS,
// transposed, unrolled/static). Compute reads LDS directly (dynamic LDS
// indexing is free -- never a register array with runtime index).
// buf layout: [col][row], row-stride LP=65.
//
// REGISTER DISCIPLINE (the r5/r6 lesson): the allocator pins VGPR=84
// regardless of launch_bounds / waves_per_eu attributes; anything with
// peak-live > 84 spills (~58 MB of scratch evictions in WRITE_SIZE).
// So every phase below is shaped to keep peak live regs <= ~80:
//   - x1 staged in 4 chunks of 24 cols (24 in-flight regs, not 48)
//   - z0 computed one 32-col half at a time (one acc[32], reused)
//   - s1[16..31] parked in spare LDS cols 32..47; s1[0..15] in regs
// ---------------------------------------------------------------------------
template<int W>
struct Stage {
    float4 v[W / 4];

    __device__ __forceinline__ void issue(const float* __restrict__ g,
                                          int lane, int rmax)
    {
        constexpr int NF4 = W / 4;
#pragma unroll
        for (int k = 0; k < NF4; ++k) {
            int id = k * 64 + lane;
            int r = id / NF4, gg = id % NF4;
            int rr = r <= rmax ? r : rmax;     // clamp (dup rows, benign)
            v[k] = *(const float4*)(g + rr * ROW_F + 4 * gg);
        }
    }

    __device__ __forceinline__ void commitL(float* buf, int lane)
    {
        constexpr int NF4 = W / 4;
        wave_fence();                          // WAR vs previous buf consumers
#pragma unroll
        for (int k = 0; k < NF4; ++k) {
            int id = k * 64 + lane;
            int r = id / NF4, gg = id % NF4;
            buf[(4 * gg + 0) * LP + r] = v[k].x;
            buf[(4 * gg + 1) * LP + r] = v[k].y;
            buf[(4 * gg + 2) * LP + r] = v[k].z;
            buf[(4 * gg + 3) * LP + r] = v[k].w;
        }
        wave_fence();
    }
};

// coalesced store of W cols already sitting in buf (transposed read + store)
template<int W>
__device__ __forceinline__ void flushL(float* __restrict__ g, const float* buf,
                                       int lane, int rmax)
{
    constexpr int NF4 = W / 4;
    wave_fence();                          // all lanes' gate writes visible
#pragma unroll
    for (int k = 0; k < NF4; ++k) {
        int id = k * 64 + lane;
        int r = id / NF4, gg = id % NF4;
        int rr = r <= rmax ? r : rmax;     // dup rows write identical data
        float4 o;
        o.x = buf[(4 * gg + 0) * LP + r];
        o.y = buf[(4 * gg + 1) * LP + r];
        o.z = buf[(4 * gg + 2) * LP + r];
        o.w = buf[(4 * gg + 3) * LP + r];
        *(float4*)(g + rr * ROW_F + 4 * gg) = o;
    }
}

// ---------------------------------------------------------------------------
// Kernel 2: 2 waves/block, one row per lane, 25 KB LDS (6 blocks/CU).
// ---------------------------------------------------------------------------
__global__ __launch_bounds__(TPB)
void field_main(const float* __restrict__ in,     // N x 160
                const float* __restrict__ attr,   // N
                const float* __restrict__ field,  // N x 3
                const float* __restrict__ Wg,     // 4096 floats: W0c | W1c
                float* __restrict__ out,          // N x 160
                int nrows)
{
    __shared__ float tbuf[WPB][48 * LP];

    const int tid = threadIdx.x;
    const int wv = tid >> 6, lane = tid & 63;
    int r0 = (blockIdx.x * WPB + wv) * 64;
    if (r0 > nrows - 64) r0 = nrows - 64;          // overflow waves: dup work
    if (r0 < 0) r0 = 0;
    const int rmax = min(63, nrows - 1 - r0);
    const int rowe = r0 + min(lane, rmax);

    const float a  = attr[rowe];
    const float f0 = field[3 * rowe + 0];
    const float f1 = field[3 * rowe + 1];
    const float f2 = field[3 * rowe + 2];
    const float af0 = a * f0, af1 = a * f1, af2 = a * f2;

    const float* gin  = in  + (size_t)r0 * ROW_F;
    float*       gout = out + (size_t)r0 * ROW_F;
    float* buf = tbuf[wv];

    // ---- x0 halves in flight together ----
    Stage<32> XA, XB;
    XA.issue(gin,      lane, rmax);
    XB.issue(gin + 32, lane, rmax);

    XA.commitL(buf, lane);                 // buf cols 0..31 = x0[0..32)

    Stage<24> CA, CB;                      // x1 ping-pong staging (24 cols)
    CA.issue(gin + 64, lane, rmax);        // latency hides under pw loop 0

    // ---- pw[w] = a * sum_u x0[u] * W1c[u][w]; x0 from LDS, rolled ----
    float pw[32];
#pragma unroll
    for (int w = 0; w < 32; ++w) pw[w] = 0.f;

#pragma unroll 2
    for (int u = 0; u < 32; ++u) {
        const float xu = buf[u * LP + lane];
        const float4* wr = (const float4*)(Wg + 2048 + u * 32);
#pragma unroll
        for (int j = 0; j < 8; ++j) {
            const float4 t = wr[j];
            pw[4 * j + 0] += xu * t.x;
            pw[4 * j + 1] += xu * t.y;
            pw[4 * j + 2] += xu * t.z;
            pw[4 * j + 3] += xu * t.w;
        }
    }
    XB.commitL(buf, lane);                 // buf cols 0..31 = x0[32..64)
#pragma unroll 2
    for (int u = 0; u < 32; ++u) {
        const float xu = buf[u * LP + lane];
        const float4* wr = (const float4*)(Wg + 3072 + u * 32);
#pragma unroll
        for (int j = 0; j < 8; ++j) {
            const float4 t = wr[j];
            pw[4 * j + 0] += xu * t.x;
            pw[4 * j + 1] += xu * t.y;
            pw[4 * j + 2] += xu * t.z;
            pw[4 * j + 3] += xu * t.w;
        }
    }
#pragma unroll
    for (int w = 0; w < 32; ++w) pw[w] *= a;

    // ---- x1 in 4 chunks of 24 cols (8 triplets each): gate in LDS,
    //      s1 in static regs, one-chunk-ahead prefetch ----
    float s1[32];

#define X1_CHUNK(CUR, NXT, CIDX, DO_PREFETCH)                                  \
    {                                                                          \
        CUR.commitL(buf, lane);                                                \
        if (DO_PREFETCH) NXT.issue(gin + 64 + 24 * ((CIDX) + 1), lane, rmax);  \
        _Pragma("unroll")                                                      \
        for (int i = 0; i < 8; ++i) {                                          \
            const int u = 8 * (CIDX) + i;                                      \
            const float m0 = buf[(3 * i + 0) * LP + lane];                     \
            const float m1 = buf[(3 * i + 1) * LP + lane];                     \
            const float m2 = buf[(3 * i + 2) * LP + lane];                     \
            s1[u] = m0 * af0 + m1 * af1 + m2 * af2;                            \
            const float p = pw[u];                                             \
            float q0 = m0 + p * f0;                                            \
            float q1 = m1 + p * f1;                                            \
            float q2 = m2 + p * f2;                                            \
            float n = sqrtf(q0 * q0 + q1 * q1 + q2 * q2 + EPS2);               \
            float t = ssp_over_n(n);                                           \
            buf[(3 * i + 0) * LP + lane] = q0 * t;                             \
            buf[(3 * i + 1) * LP + lane] = q1 * t;                             \
            buf[(3 * i + 2) * LP + lane] = q2 * t;                             \
        }                                                                      \
        flushL<24>(gout + 64 + 24 * (CIDX), buf, lane, rmax);                  \
    }

    X1_CHUNK(CA, CB, 0, true)
    X1_CHUNK(CB, CA, 1, true)
    X1_CHUNK(CA, CB, 2, true)
    X1_CHUNK(CB, CA, 3, false)
#undef X1_CHUNK

    // ---- park s1[16..31] in spare LDS cols 32..47 (frees 16 regs);
    //      s1[0..15] stays in registers (static unroll below) ----
    wave_fence();
#pragma unroll
    for (int i = 0; i < 16; ++i) buf[(32 + i) * LP + lane] = s1[16 + i];
    wave_fence();

    // ---- z0 = s1 @ W0c, one 32-col half at a time (acc reused) ----
    Stage<32> XR;
    XR.issue(gin, lane, rmax);             // x0 re-read; hides under z0 half 0

    float acc[32];
#pragma unroll
    for (int j = 0; j < 32; ++j) acc[j] = 0.f;
#pragma unroll
    for (int u = 0; u < 16; ++u) {         // s1 lo from regs (static)
        const float su = s1[u];
        const float4* wr = (const float4*)(Wg + u * 64);
#pragma unroll
        for (int j = 0; j < 8; ++j) {
            const float4 t = wr[j];
            acc[4 * j + 0] += su * t.x;
            acc[4 * j + 1] += su * t.y;
            acc[4 * j + 2] += su * t.z;
            acc[4 * j + 3] += su * t.w;
        }
    }
#pragma unroll 2
    for (int i = 0; i < 16; ++i) {         // s1 hi from LDS (rolled)
        const float su = buf[(32 + i) * LP + lane];
        const float4* wr = (const float4*)(Wg + (16 + i) * 64);
#pragma unroll
        for (int j = 0; j < 8; ++j) {
            const float4 t = wr[j];
            acc[4 * j + 0] += su * t.x;
            acc[4 * j + 1] += su * t.y;
            acc[4 * j + 2] += su * t.z;
            acc[4 * j + 3] += su * t.w;
        }
    }

    XR.commitL(buf, lane);                 // cols 0..31 = x0[0..32)
    Stage<32> XS;
    XS.issue(gin + 32, lane, rmax);        // hides under gate + z0 half 1
#pragma unroll
    for (int j = 0; j < 32; ++j) {
        const float r = buf[j * LP + lane] + acc[j];
        const float n = sqrtf(r * r + EPS2);
        buf[j * LP + lane] = r * ssp_over_n(n);
    }
    flushL<32>(gout, buf, lane, rmax);

#pragma unroll
    for (int j = 0; j < 32; ++j) acc[j] = 0.f;
#pragma unroll
    for (int u = 0; u < 16; ++u) {
        const float su = s1[u];
        const float4* wr = (const float4*)(Wg + u * 64 + 32);
#pragma unroll
        for (int j = 0; j < 8; ++j) {
            const float4 t = wr[j];
            acc[4 * j + 0] += su * t.x;
            acc[4 * j + 1] += su * t.y;
            acc[4 * j + 2] += su * t.z;
            acc[4 * j + 3] += su * t.w;
        }
    }
#pragma unroll 2
    for (int i = 0; i < 16; ++i) {
        const float su = buf[(32 + i) * LP + lane];
        const float4* wr = (const float4*)(Wg + (16 + i) * 64 + 32);
#pragma unroll
        for (int j = 0; j < 8; ++j) {
            const float4 t = wr[j];
            acc[4 * j + 0] += su * t.x;
            acc[4 * j + 1] += su * t.y;
            acc[4 * j + 2] += su * t.z;
            acc[4 * j + 3] += su * t.w;
        }
    }

    XS.commitL(buf, lane);                 // cols 0..31 = x0[32..64)
#pragma unroll
    for (int j = 0; j < 32; ++j) {
        const float r = buf[j * LP + lane] + acc[j];
        const float n = sqrtf(r * r + EPS2);
        buf[j * LP + lane] = r * ssp_over_n(n);
    }
    flushL<32>(gout + 32, buf, lane, rmax);
}

extern "C" void kernel_launch(void* const* d_in, const int* in_sizes, int n_in,
                              void* d_out, int out_size, void* d_ws, size_t ws_size,
                              hipStream_t stream)
{
    const float* node_input = (const float*)d_in[0];
    const float* node_attr  = (const float*)d_in[1];
    const float* field      = (const float*)d_in[2];
    const float* Wtp0       = (const float*)d_in[3];
    const float* Wtp1       = (const float*)d_in[4];
    const float* Wlin0      = (const float*)d_in[5];
    const float* Wlin1      = (const float*)d_in[6];
    const float* Wsc0       = (const float*)d_in[7];
    const float* Wsc1       = (const float*)d_in[8];
    float* out = (float*)d_out;
    float* ws  = (float*)d_ws;

    const int nrows = in_sizes[0] / ROW_F;   // 200000

    hipLaunchKernelGGL(combine_weights, dim3(1), dim3(1024), 0, stream,
                       Wtp0, Wtp1, Wlin0, Wlin1, Wsc0, Wsc1, ws);

    const int nwaves = (nrows + 63) / 64;
    const int nb = (nwaves + WPB - 1) / WPB;
    hipLaunchKernelGGL(field_main, dim3(nb), dim3(TPB), 0, stream,
                       node_input, node_attr, field, ws, out, nrows);
}